// Round 2
// baseline (3958.040 us; speedup 1.0000x reference)
//
#include <hip/hip_runtime.h>
#include <hip/hip_bf16.h>

// Problem constants (fixed-shape problem)
#define NSEQ 1024   // N = (N_UTT-1)*B
#define LS   128    // L
#define ED   256    // E
#define HD   256    // H
#define BSZ  256    // batch
#define UTT  4      // U = n-1
#define KP   1280   // (MAX_UTT-1)*H

using short8 = __attribute__((ext_vector_type(8))) short;
using f32x4  = __attribute__((ext_vector_type(4))) float;

union S8 { short8 s; unsigned u[4]; };

__device__ __forceinline__ unsigned pack_bf2(float a, float b){
  unsigned ua = __builtin_bit_cast(unsigned, a);
  unsigned ub = __builtin_bit_cast(unsigned, b);
  return ((ua + 0x8000u) >> 16) | ((ub + 0x8000u) & 0xFFFF0000u);
}
__device__ __forceinline__ unsigned short f2bf(float a){
  return (unsigned short)((__builtin_bit_cast(unsigned, a) + 0x8000u) >> 16);
}
// convert 8 consecutive f32 -> short8 of bf16 bits
__device__ __forceinline__ short8 cvt8(const float* __restrict__ p){
  float4 a = ((const float4*)p)[0];
  float4 b = ((const float4*)p)[1];
  S8 s;
  s.u[0] = pack_bf2(a.x, a.y); s.u[1] = pack_bf2(a.z, a.w);
  s.u[2] = pack_bf2(b.x, b.y); s.u[3] = pack_bf2(b.z, b.w);
  return s.s;
}
__device__ __forceinline__ float sigm(float x){ return 1.0f/(1.0f + exp2f(-1.44269504f*x)); }
__device__ __forceinline__ float tanh_f(float x){ return 2.0f/(1.0f + exp2f(-2.88539008f*x)) - 1.0f; }
// LDS bank-conflict swizzle on 16B granules within a 512B row (G4 pattern)
__device__ __forceinline__ int swz(int row, int gr){ return (gr & 24) | ((gr ^ row) & 7); }

// ---------------- kernel 0: emb f32 -> bf16 (optional, ws-gated) ----------
__global__ void k_cvt(const float* __restrict__ e, unsigned short* __restrict__ o, int n8){
  int i = blockIdx.x * blockDim.x + threadIdx.x;
  if (i < n8) *(short8*)(o + (size_t)i*8) = cvt8(e + (size_t)i*8);
}

// ---------------- kernel 1: se[seq][e] = sum_t emb[idx[seq][t]][e] --------
__global__ void k_se(const int* __restrict__ bi, const float* __restrict__ emb,
                     float* __restrict__ se){
  int seq = blockIdx.x, e = threadIdx.x;
  const int* row = bi + seq * LS;
  float acc = 0.f;
  #pragma unroll 4
  for (int t = 0; t < LS; ++t) acc += emb[(size_t)row[t]*ED + e];
  se[seq*ED + e] = acc;
}

// ---------------- kernel 2: cosine + softmax -> weight[b][u] --------------
__global__ void k_weight(const float* __restrict__ se, float* __restrict__ wgt){
  int b = blockIdx.x, l = threadIdx.x;  // 64 threads
  const float* s3 = se + (b*UTT + 3)*ED;
  float dots[UTT], nn[UTT];
  #pragma unroll
  for (int u = 0; u < UTT; ++u){
    const float* su = se + (b*UTT + u)*ED;
    float d = 0.f, q = 0.f;
    for (int k = l; k < ED; k += 64){ float a = su[k]; d += a * s3[k]; q += a * a; }
    #pragma unroll
    for (int off = 32; off; off >>= 1){ d += __shfl_xor(d, off); q += __shfl_xor(q, off); }
    dots[u] = d; nn[u] = q;
  }
  if (l == 0){
    float n3 = fmaxf(sqrtf(nn[3]), 1e-8f);
    float c[UTT], m = -1e30f;
    #pragma unroll
    for (int u = 0; u < UTT; ++u){
      float nu = fmaxf(sqrtf(nn[u]), 1e-8f);
      c[u] = dots[u] / (nu * n3);
      m = fmaxf(m, c[u]);
    }
    float s = 0.f;
    #pragma unroll
    for (int u = 0; u < UTT; ++u){ c[u] = exp2f(1.44269504f*(c[u]-m)); s += c[u]; }
    #pragma unroll
    for (int u = 0; u < UTT; ++u) wgt[b*UTT + u] = c[u] / s;
  }
}

// ---------------- kernel 3: main masked LSTM ------------------------------
// 64 blocks x 16 seqs. 16 waves/block; wave w owns gate cols {16w..16w+15}
// of each gate group => cell update is wave-local. Weights in registers
// (bf16 frags). h exchanged via double-buffered swizzled LDS; 1 barrier/step.
// enc written f32 straight from registers (value = mask ? h_new : 0).
template<bool EB>
__launch_bounds__(1024)
__global__ void k_lstm_main(const int* __restrict__ bi, const int* __restrict__ lens,
                            const float* __restrict__ embf, const unsigned short* __restrict__ embb,
                            const float* __restrict__ Wih, const float* __restrict__ Whh,
                            const float* __restrict__ bb,
                            float* __restrict__ enc,
                            float* __restrict__ hT, float* __restrict__ cT)
{
  const int w  = threadIdx.x >> 6;   // wave 0..15
  const int l  = threadIdx.x & 63;
  const int lm = l & 15;             // A-row / D-col lane index
  const int lg = l >> 4;             // 0..3 (k-block / D-row group)
  const int seqbase = blockIdx.x * 16;

  __shared__ short hbuf[2][16*256];  // bf16 bits, swizzled 16B granules

  for (int i = threadIdx.x; i < 16*256; i += 1024) hbuf[0][i] = 0;

  // bias per gate group for my column
  float bias[4];
  #pragma unroll
  for (int g = 0; g < 4; ++g) bias[g] = bb[g*HD + w*16 + lm];

  // persistent weight fragments: W[n][k], n = g*256 + 16w + lm, k = kc*32 + lg*8 + j
  short8 wih[4][8], whh[4][8];
  #pragma unroll
  for (int g = 0; g < 4; ++g){
    const float* pw = Wih + (size_t)(g*HD + w*16 + lm)*ED + lg*8;
    const float* ph = Whh + (size_t)(g*HD + w*16 + lm)*HD + lg*8;
    #pragma unroll
    for (int kc = 0; kc < 8; ++kc){
      wih[g][kc] = cvt8(pw + kc*32);
      whh[g][kc] = cvt8(ph + kc*32);
    }
  }

  int len_r[4];
  #pragma unroll
  for (int r = 0; r < 4; ++r) len_r[r] = lens[seqbase + lg*4 + r];

  float h_reg[4] = {0,0,0,0};   // h,c for (seq = lg*4+r, comp = 16w+lm)
  float c_reg[4] = {0,0,0,0};

  const int* myrow = bi + (size_t)(seqbase + lm) * LS;
  const int  mycol = w*16 + lm;

  __syncthreads();

  int p = 0;
  for (int t = 0; t < LS; ++t){
    // ---- x fragments (global) ----
    int idx = myrow[t];
    short8 xf[8];
    if constexpr (EB){
      const unsigned short* xr = embb + (size_t)idx*ED + lg*8;
      #pragma unroll
      for (int kc = 0; kc < 8; ++kc) xf[kc] = *(const short8*)(xr + kc*32);
    } else {
      const float* xr = embf + (size_t)idx*ED + lg*8;
      #pragma unroll
      for (int kc = 0; kc < 8; ++kc) xf[kc] = cvt8(xr + kc*32);
    }
    // ---- h fragments (LDS, swizzled) ----
    short8 hf[8];
    const short* hb = &hbuf[p][0];
    #pragma unroll
    for (int kc = 0; kc < 8; ++kc){
      int gr = kc*4 + lg;
      hf[kc] = *(const short8*)(hb + lm*256 + swz(lm, gr)*8);
    }
    // ---- MFMA: g = x@Wih^T + h@Whh^T + b ----
    f32x4 acc[4];
    #pragma unroll
    for (int g = 0; g < 4; ++g){ f32x4 a = {bias[g],bias[g],bias[g],bias[g]}; acc[g] = a; }
    #pragma unroll
    for (int kc = 0; kc < 8; ++kc){
      #pragma unroll
      for (int g = 0; g < 4; ++g)
        acc[g] = __builtin_amdgcn_mfma_f32_16x16x32_bf16(xf[kc], wih[g][kc], acc[g], 0, 0, 0);
    }
    #pragma unroll
    for (int kc = 0; kc < 8; ++kc){
      #pragma unroll
      for (int g = 0; g < 4; ++g)
        acc[g] = __builtin_amdgcn_mfma_f32_16x16x32_bf16(hf[kc], whh[g][kc], acc[g], 0, 0, 0);
    }
    // ---- cell update (wave-local), write h' to other LDS buffer ----
    short* hbn = &hbuf[p^1][0];
    #pragma unroll
    for (int r = 0; r < 4; ++r){
      float gi = sigm(acc[0][r]);
      float gf = sigm(acc[1][r]);
      float gg = tanh_f(acc[2][r]);
      float go = sigm(acc[3][r]);
      float cn = gf * c_reg[r] + gi * gg;
      float hn = go * tanh_f(cn);
      bool mk = (t < len_r[r]);
      c_reg[r] = mk ? cn : c_reg[r];
      h_reg[r] = mk ? hn : h_reg[r];
      int row = lg*4 + r;
      hbn[row*256 + swz(row, mycol >> 3)*8 + (mycol & 7)] = f2bf(h_reg[r]);
      // enc[seq][t][col] = m * h_new, f32 straight from registers
      enc[ ((size_t)(seqbase + row)*LS + t)*HD + mycol ] = mk ? hn : 0.f;
    }
    __syncthreads();
    p ^= 1;
  }
  // ---- epilogue: hT, cT (f32 scratch) ----
  #pragma unroll
  for (int r = 0; r < 4; ++r){
    int row = seqbase + lg*4 + r;
    hT[row*HD + mycol] = h_reg[r];
    cT[row*HD + mycol] = c_reg[r];
  }
}

// ---------------- kernel 4: branch LSTMs (4 steps, unmasked) --------------
// 32 blocks: branch = bid>>4 (0=h,1=c), 16 batch rows per block.
// Writes P[b][u*256+c] = h_u[b][c] * weight[b][u]; pad slot zeroed.
__launch_bounds__(1024)
__global__ void k_branch(const float* __restrict__ stateH, const float* __restrict__ stateC,
                         const float* __restrict__ WiH, const float* __restrict__ WhH, const float* __restrict__ bH,
                         const float* __restrict__ WiC, const float* __restrict__ WhC, const float* __restrict__ bC,
                         const float* __restrict__ wgt,
                         float* __restrict__ PH, float* __restrict__ PC)
{
  const int branch = blockIdx.x >> 4;
  const int blk    = blockIdx.x & 15;
  const float* state = branch ? stateC : stateH;
  const float* Wi    = branch ? WiC : WiH;
  const float* Wh    = branch ? WhC : WhH;
  const float* bb    = branch ? bC  : bH;
  float* P           = branch ? PC  : PH;

  const int w  = threadIdx.x >> 6;
  const int l  = threadIdx.x & 63;
  const int lm = l & 15;
  const int lg = l >> 4;
  const int rbase = blk * 16;

  __shared__ short hbuf[2][16*256];
  for (int i = threadIdx.x; i < 16*256; i += 1024) hbuf[0][i] = 0;
  // zero the pad-utterance slot
  for (int i = threadIdx.x; i < 16*256; i += 1024)
    P[(size_t)(rbase + (i >> 8))*KP + UTT*HD + (i & 255)] = 0.f;

  float bias[4];
  #pragma unroll
  for (int g = 0; g < 4; ++g) bias[g] = bb[g*HD + w*16 + lm];

  short8 wih[4][8], whh[4][8];
  #pragma unroll
  for (int g = 0; g < 4; ++g){
    const float* pw = Wi + (size_t)(g*HD + w*16 + lm)*HD + lg*8;
    const float* ph = Wh + (size_t)(g*HD + w*16 + lm)*HD + lg*8;
    #pragma unroll
    for (int kc = 0; kc < 8; ++kc){
      wih[g][kc] = cvt8(pw + kc*32);
      whh[g][kc] = cvt8(ph + kc*32);
    }
  }

  float c_reg[4] = {0,0,0,0};
  __syncthreads();

  int p = 0;
  for (int u = 0; u < UTT; ++u){
    // x_u[b] = state[b*4 + u], b = rbase + lm
    const float* xr = state + (size_t)((rbase + lm)*UTT + u)*HD + lg*8;
    short8 xf[8];
    #pragma unroll
    for (int kc = 0; kc < 8; ++kc) xf[kc] = cvt8(xr + kc*32);
    short8 hf[8];
    const short* hb = &hbuf[p][0];
    #pragma unroll
    for (int kc = 0; kc < 8; ++kc){
      int gr = kc*4 + lg;
      hf[kc] = *(const short8*)(hb + lm*256 + swz(lm, gr)*8);
    }
    f32x4 acc[4];
    #pragma unroll
    for (int g = 0; g < 4; ++g){ f32x4 a = {bias[g],bias[g],bias[g],bias[g]}; acc[g] = a; }
    #pragma unroll
    for (int kc = 0; kc < 8; ++kc){
      #pragma unroll
      for (int g = 0; g < 4; ++g)
        acc[g] = __builtin_amdgcn_mfma_f32_16x16x32_bf16(xf[kc], wih[g][kc], acc[g], 0, 0, 0);
    }
    #pragma unroll
    for (int kc = 0; kc < 8; ++kc){
      #pragma unroll
      for (int g = 0; g < 4; ++g)
        acc[g] = __builtin_amdgcn_mfma_f32_16x16x32_bf16(hf[kc], whh[g][kc], acc[g], 0, 0, 0);
    }
    short* hbn = &hbuf[p^1][0];
    #pragma unroll
    for (int r = 0; r < 4; ++r){
      float gi = sigm(acc[0][r]);
      float gf = sigm(acc[1][r]);
      float gg = tanh_f(acc[2][r]);
      float go = sigm(acc[3][r]);
      float cn = gf * c_reg[r] + gi * gg;
      float hn = go * tanh_f(cn);
      c_reg[r] = cn;
      int row = lg*4 + r, c = w*16 + lm;
      hbn[row*256 + swz(row, c >> 3)*8 + (c & 7)] = f2bf(hn);
      int b = rbase + row;
      P[(size_t)b*KP + u*HD + c] = hn * wgt[b*UTT + u];
    }
    __syncthreads();
    p ^= 1;
  }
}

// ---------------- kernel 5: final projection out = P @ Wl^T + bl ----------
// 32 blocks (branch = bid>>4, 16 rows each) x 256 threads (4 waves, 4 tiles each)
__launch_bounds__(256)
__global__ void k_final(const float* __restrict__ PH, const float* __restrict__ PC,
                        const float* __restrict__ Wlh, const float* __restrict__ blh,
                        const float* __restrict__ Wlc, const float* __restrict__ blc,
                        float* __restrict__ outH, float* __restrict__ outC)
{
  const int branch = blockIdx.x >> 4;
  const int blk    = blockIdx.x & 15;
  const float* P  = branch ? PC  : PH;
  const float* Wl = branch ? Wlc : Wlh;
  const float* bl = branch ? blc : blh;
  float* out = branch ? outC : outH;

  const int w  = threadIdx.x >> 6;   // 0..3
  const int l  = threadIdx.x & 63;
  const int lm = l & 15;
  const int lg = l >> 4;
  const int rbase = blk * 16;

  f32x4 acc[4];
  #pragma unroll
  for (int j = 0; j < 4; ++j){
    float bv = bl[(w*4 + j)*16 + lm];
    f32x4 a = {bv, bv, bv, bv}; acc[j] = a;
  }
  for (int kc = 0; kc < 40; ++kc){
    short8 af = cvt8(P + (size_t)(rbase + lm)*KP + kc*32 + lg*8);
    #pragma unroll
    for (int j = 0; j < 4; ++j){
      int n = (w*4 + j)*16 + lm;
      short8 bf_ = cvt8(Wl + (size_t)n*KP + kc*32 + lg*8);
      acc[j] = __builtin_amdgcn_mfma_f32_16x16x32_bf16(af, bf_, acc[j], 0, 0, 0);
    }
  }
  #pragma unroll
  for (int j = 0; j < 4; ++j)
    #pragma unroll
    for (int r = 0; r < 4; ++r)
      out[(size_t)(rbase + lg*4 + r)*HD + (w*4 + j)*16 + lm] = acc[j][r];
}

// ---------------- launch ---------------------------------------------------
extern "C" void kernel_launch(void* const* d_in, const int* in_sizes, int n_in,
                              void* d_out, int out_size, void* d_ws, size_t ws_size,
                              hipStream_t stream)
{
  (void)in_sizes; (void)n_in; (void)out_size;
  const int*   bi   = (const int*)  d_in[0];
  const int*   lens = (const int*)  d_in[1];
  const float* emb  = (const float*)d_in[7];
  const float* Wih  = (const float*)d_in[8];
  const float* Whh  = (const float*)d_in[9];
  const float* bb   = (const float*)d_in[10];
  const float* WiH  = (const float*)d_in[11];
  const float* WhH  = (const float*)d_in[12];
  const float* bH   = (const float*)d_in[13];
  const float* WiC  = (const float*)d_in[14];
  const float* WhC  = (const float*)d_in[15];
  const float* bC   = (const float*)d_in[16];
  const float* Wlh  = (const float*)d_in[17];
  const float* blh  = (const float*)d_in[18];
  const float* Wlc  = (const float*)d_in[19];
  const float* blc  = (const float*)d_in[20];

  // ws layout (floats): se | weight | hT | cT | P_h | P_c ; emb_bf16 @ +6MB
  float* ws  = (float*)d_ws;
  float* se  = ws;
  float* wgt = ws + 262144;
  float* hT  = ws + 263168;
  float* cT  = ws + 525312;
  float* PH  = ws + 787456;
  float* PC  = ws + 1115136;
  unsigned short* embb = (unsigned short*)((char*)d_ws + (6u << 20));
  const bool use_bf = (ws_size >= ((6ull << 20) + 2ull * 32000 * 256));

  float* enc  = (float*)d_out;                        // f32 outputs
  float* outH = enc + (size_t)NSEQ * LS * HD;         // 33,554,432
  float* outC = outH + (size_t)BSZ * HD;              // +65,536

  if (use_bf) k_cvt<<<4000, 256, 0, stream>>>(emb, embb, 32000*256/8);
  k_se    <<<NSEQ, 256, 0, stream>>>(bi, emb, se);
  k_weight<<<BSZ,   64, 0, stream>>>(se, wgt);
  if (use_bf)
    k_lstm_main<true ><<<64, 1024, 0, stream>>>(bi, lens, emb, embb, Wih, Whh, bb, enc, hT, cT);
  else
    k_lstm_main<false><<<64, 1024, 0, stream>>>(bi, lens, emb, embb, Wih, Whh, bb, enc, hT, cT);
  k_branch<<<32, 1024, 0, stream>>>(hT, cT, WiH, WhH, bH, WiC, WhC, bC, wgt, PH, PC);
  k_final <<<32,  256, 0, stream>>>(PH, PC, Wlh, blh, Wlc, blc, outH, outC);
}

// Round 3
// 1918.608 us; speedup vs baseline: 2.0630x; 2.0630x over previous
//
#include <hip/hip_runtime.h>
#include <hip/hip_bf16.h>

// Problem constants (fixed-shape problem)
#define NSEQ 1024   // N = (N_UTT-1)*B
#define LS   128    // L
#define ED   256    // E
#define HD   256    // H
#define BSZ  256    // batch
#define UTT  4      // U = n-1
#define KP   1280   // (MAX_UTT-1)*H

using short8 = __attribute__((ext_vector_type(8))) short;
using f32x4  = __attribute__((ext_vector_type(4))) float;

union S8 { short8 s; unsigned u[4]; };

__device__ __forceinline__ unsigned pack_bf2(float a, float b){
  unsigned ua = __builtin_bit_cast(unsigned, a);
  unsigned ub = __builtin_bit_cast(unsigned, b);
  return ((ua + 0x8000u) >> 16) | ((ub + 0x8000u) & 0xFFFF0000u);
}
__device__ __forceinline__ unsigned short f2bf(float a){
  return (unsigned short)((__builtin_bit_cast(unsigned, a) + 0x8000u) >> 16);
}
__device__ __forceinline__ float bf2f(unsigned short u){
  unsigned v = ((unsigned)u) << 16;
  return __builtin_bit_cast(float, v);
}
// convert 8 consecutive f32 -> short8 of bf16 bits
__device__ __forceinline__ short8 cvt8(const float* __restrict__ p){
  float4 a = ((const float4*)p)[0];
  float4 b = ((const float4*)p)[1];
  S8 s;
  s.u[0] = pack_bf2(a.x, a.y); s.u[1] = pack_bf2(a.z, a.w);
  s.u[2] = pack_bf2(b.x, b.y); s.u[3] = pack_bf2(b.z, b.w);
  return s.s;
}
__device__ __forceinline__ float sigm(float x){ return 1.0f/(1.0f + exp2f(-1.44269504f*x)); }
__device__ __forceinline__ float tanh_f(float x){ return 2.0f/(1.0f + exp2f(-2.88539008f*x)) - 1.0f; }
__device__ __forceinline__ int swz(int row, int gr){ return (gr & 24) | ((gr ^ row) & 7); }

// ---------------- init: zero sync flags (must run each launch; replay-safe)
__global__ void k_init(int* __restrict__ flags){
  flags[threadIdx.x] = 0;
}

// ---------------- cvt Wih f32 -> bf16 -------------------------------------
__global__ void k_cvtW(const float* __restrict__ e, unsigned short* __restrict__ o, int n8){
  int i = blockIdx.x * blockDim.x + threadIdx.x;
  if (i < n8) *(short8*)(o + (size_t)i*8) = cvt8(e + (size_t)i*8);
}

// ---------------- vocab projection: proj[v][g*256+c] = Wih@emb[v] + b ------
// 1000 blocks x 256 thr (4 waves). Wave = gate g; M=32 rows; N=256; K=256.
__launch_bounds__(256, 2)
__global__ void k_proj(const float* __restrict__ emb, const unsigned short* __restrict__ WihB,
                       const float* __restrict__ bb, unsigned short* __restrict__ proj)
{
  const int g  = threadIdx.x >> 6;    // gate 0..3
  const int l  = threadIdx.x & 63;
  const int lm = l & 15;
  const int lg = l >> 4;
  const int vbase = blockIdx.x * 32;

  f32x4 acc[2][16];
  #pragma unroll
  for (int j = 0; j < 16; ++j){
    float bv = bb[g*256 + j*16 + lm];
    f32x4 a = {bv, bv, bv, bv};
    acc[0][j] = a; acc[1][j] = a;
  }
  for (int kc = 0; kc < 8; ++kc){
    short8 af0 = cvt8(emb + (size_t)(vbase + lm)*ED + kc*32 + lg*8);
    short8 af1 = cvt8(emb + (size_t)(vbase + 16 + lm)*ED + kc*32 + lg*8);
    #pragma unroll
    for (int j = 0; j < 16; ++j){
      short8 bf_ = *(const short8*)(WihB + (size_t)(g*256 + j*16 + lm)*ED + kc*32 + lg*8);
      acc[0][j] = __builtin_amdgcn_mfma_f32_16x16x32_bf16(af0, bf_, acc[0][j], 0, 0, 0);
      acc[1][j] = __builtin_amdgcn_mfma_f32_16x16x32_bf16(af1, bf_, acc[1][j], 0, 0, 0);
    }
  }
  #pragma unroll
  for (int m2 = 0; m2 < 2; ++m2)
    #pragma unroll
    for (int j = 0; j < 16; ++j)
      #pragma unroll
      for (int r = 0; r < 4; ++r){
        int v = vbase + m2*16 + lg*4 + r;
        proj[(size_t)v*1024 + g*256 + j*16 + lm] = f2bf(acc[m2][j][r]);
      }
}

// ---------------- kernel 1: se[seq][e] = sum_t emb[idx[seq][t]][e] --------
__global__ void k_se(const int* __restrict__ bi, const float* __restrict__ emb,
                     float* __restrict__ se){
  int seq = blockIdx.x, e = threadIdx.x;
  const int* row = bi + seq * LS;
  float acc = 0.f;
  #pragma unroll 4
  for (int t = 0; t < LS; ++t) acc += emb[(size_t)row[t]*ED + e];
  se[seq*ED + e] = acc;
}

// ---------------- kernel 2: cosine + softmax -> weight[b][u] --------------
__global__ void k_weight(const float* __restrict__ se, float* __restrict__ wgt){
  int b = blockIdx.x, l = threadIdx.x;  // 64 threads
  const float* s3 = se + (b*UTT + 3)*ED;
  float dots[UTT], nn[UTT];
  #pragma unroll
  for (int u = 0; u < UTT; ++u){
    const float* su = se + (b*UTT + u)*ED;
    float d = 0.f, q = 0.f;
    for (int k = l; k < ED; k += 64){ float a = su[k]; d += a * s3[k]; q += a * a; }
    #pragma unroll
    for (int off = 32; off; off >>= 1){ d += __shfl_xor(d, off); q += __shfl_xor(q, off); }
    dots[u] = d; nn[u] = q;
  }
  if (l == 0){
    float n3 = fmaxf(sqrtf(nn[3]), 1e-8f);
    float c[UTT], m = -1e30f;
    #pragma unroll
    for (int u = 0; u < UTT; ++u){
      float nu = fmaxf(sqrtf(nn[u]), 1e-8f);
      c[u] = dots[u] / (nu * n3);
      m = fmaxf(m, c[u]);
    }
    float s = 0.f;
    #pragma unroll
    for (int u = 0; u < UTT; ++u){ c[u] = exp2f(1.44269504f*(c[u]-m)); s += c[u]; }
    #pragma unroll
    for (int u = 0; u < UTT; ++u) wgt[b*UTT + u] = c[u] / s;
  }
}

// ---------------- cooperative recurrence (2-way column split) --------------
// 128 blocks: slice s = bid>>6 (cols [s*128, s*128+128) of h), group g = bid&63
// (seqs 16g..16g+15). Partner = bid +/- 64 -> same XCD (bid%8 round-robin).
// Each of 8 waves holds Whh frags for 4 gates x 16 cols in registers (128 VGPR).
// Input projection pre-gathered from proj[] (bias folded). h exchanged through
// double-buffered global hx + monotone flags (release/acquire, AGENT scope).
__device__ __forceinline__ void load_xp(const int* __restrict__ bi,
                                        const unsigned short* __restrict__ proj,
                                        int sb, int lg, int mycol, int t,
                                        float xp[4][4]){
  #pragma unroll
  for (int r = 0; r < 4; ++r){
    int tok = bi[(sb + lg*4 + r)*LS + t];
    const unsigned short* pr = proj + (size_t)tok*1024 + mycol;
    #pragma unroll
    for (int q = 0; q < 4; ++q) xp[q][r] = bf2f(pr[q*256]);
  }
}

__launch_bounds__(512, 2)
__global__ void k_rec(const int* __restrict__ bi, const int* __restrict__ lens,
                      const unsigned short* __restrict__ proj,
                      const float* __restrict__ Whh,
                      float* __restrict__ enc,
                      float* __restrict__ hT, float* __restrict__ cT,
                      unsigned short* __restrict__ hx, int* __restrict__ flags)
{
  const int s    = blockIdx.x >> 6;       // column slice 0/1
  const int gidx = blockIdx.x & 63;       // seq group
  const int w  = threadIdx.x >> 6;        // wave 0..7
  const int l  = threadIdx.x & 63;
  const int lm = l & 15;
  const int lg = l >> 4;
  const int sb = gidx * 16;
  const int mycol = s*128 + w*16 + lm;

  // persistent Whh fragments: 4 gates x 8 k-chunks (128 VGPR)
  short8 whh[4][8];
  #pragma unroll
  for (int q = 0; q < 4; ++q){
    const float* ph = Whh + (size_t)(q*HD + mycol)*HD + lg*8;
    #pragma unroll
    for (int kc = 0; kc < 8; ++kc) whh[q][kc] = cvt8(ph + kc*32);
  }

  int len_r[4];
  #pragma unroll
  for (int r = 0; r < 4; ++r) len_r[r] = lens[sb + lg*4 + r];

  float h_reg[4] = {0,0,0,0};
  float c_reg[4] = {0,0,0,0};

  int* myflag = flags + gidx*2 + s;
  int* pflag  = flags + gidx*2 + (1 - s);
  // hx layout: [buf][group][slice][seq 16][col 128] bf16
  #define HXB(buf, s2) ( (((size_t)(buf)*64 + gidx)*2 + (s2)) * 2048 )

  float xpc[4][4], xpn[4][4];
  load_xp(bi, proj, sb, lg, mycol, 0, xpc);

  for (int t = 0; t < LS; ++t){
    short8 hf[8];
    if (t > 0){
      // ---- wait for partner's h(t-1) ----
      int v = 0; int guard = 0;
      do {
        if (l == 0) v = __hip_atomic_load(pflag, __ATOMIC_RELAXED, __HIP_MEMORY_SCOPE_AGENT);
        v = __shfl(v, 0);
      } while (v < t && ++guard < (1 << 18));
      __builtin_amdgcn_fence(__ATOMIC_ACQUIRE, "agent");
      // ---- h fragments from both slices ----
      const unsigned short* hb = hx;
      #pragma unroll
      for (int kc = 0; kc < 8; ++kc){
        int s2 = kc >> 2;
        int cl = (kc & 3)*32 + lg*8;
        hf[kc] = *(const short8*)(hb + HXB((t-1)&1, s2) + lm*128 + cl);
      }
    }
    // ---- prefetch next step's input projection (hides L3 latency) ----
    if (t + 1 < LS) load_xp(bi, proj, sb, lg, mycol, t + 1, xpn);

    // ---- gates = xp + h @ Whh_slice^T ----
    f32x4 acc[4];
    #pragma unroll
    for (int q = 0; q < 4; ++q){
      f32x4 a = {xpc[q][0], xpc[q][1], xpc[q][2], xpc[q][3]};
      acc[q] = a;
    }
    if (t > 0){
      #pragma unroll
      for (int kc = 0; kc < 8; ++kc)
        #pragma unroll
        for (int q = 0; q < 4; ++q)
          acc[q] = __builtin_amdgcn_mfma_f32_16x16x32_bf16(hf[kc], whh[q][kc], acc[q], 0, 0, 0);
    }
    // ---- cell update + outputs ----
    unsigned short* hw = hx + HXB(t&1, s);
    #pragma unroll
    for (int r = 0; r < 4; ++r){
      float gi = sigm(acc[0][r]);
      float gf = sigm(acc[1][r]);
      float gg = tanh_f(acc[2][r]);
      float go = sigm(acc[3][r]);
      float cn = gf * c_reg[r] + gi * gg;
      float hn = go * tanh_f(cn);
      bool mk = (t < len_r[r]);
      c_reg[r] = mk ? cn : c_reg[r];
      h_reg[r] = mk ? hn : h_reg[r];
      __builtin_nontemporal_store(mk ? hn : 0.f,
          enc + ((size_t)(sb + lg*4 + r)*LS + t)*HD + mycol);
      hw[(lg*4 + r)*128 + w*16 + lm] = f2bf(h_reg[r]);
    }
    __syncthreads();
    if (threadIdx.x == 0){
      __builtin_amdgcn_fence(__ATOMIC_RELEASE, "agent");
      __hip_atomic_store(myflag, t + 1, __ATOMIC_RELAXED, __HIP_MEMORY_SCOPE_AGENT);
    }
    #pragma unroll
    for (int q = 0; q < 4; ++q)
      #pragma unroll
      for (int r = 0; r < 4; ++r) xpc[q][r] = xpn[q][r];
  }
  #pragma unroll
  for (int r = 0; r < 4; ++r){
    int row = sb + lg*4 + r;
    hT[(size_t)row*HD + mycol] = h_reg[r];
    cT[(size_t)row*HD + mycol] = c_reg[r];
  }
  #undef HXB
}

// ---------------- fallback main LSTM (round-2 proven, ws-limited path) ----
__launch_bounds__(1024)
__global__ void k_lstm_main(const int* __restrict__ bi, const int* __restrict__ lens,
                            const float* __restrict__ embf,
                            const float* __restrict__ Wih, const float* __restrict__ Whh,
                            const float* __restrict__ bb,
                            float* __restrict__ enc,
                            float* __restrict__ hT, float* __restrict__ cT)
{
  const int w  = threadIdx.x >> 6;
  const int l  = threadIdx.x & 63;
  const int lm = l & 15;
  const int lg = l >> 4;
  const int seqbase = blockIdx.x * 16;

  __shared__ short hbuf[2][16*256];
  for (int i = threadIdx.x; i < 16*256; i += 1024) hbuf[0][i] = 0;

  float bias[4];
  #pragma unroll
  for (int g = 0; g < 4; ++g) bias[g] = bb[g*HD + w*16 + lm];

  short8 wih[4][8], whh[4][8];
  #pragma unroll
  for (int g = 0; g < 4; ++g){
    const float* pw = Wih + (size_t)(g*HD + w*16 + lm)*ED + lg*8;
    const float* ph = Whh + (size_t)(g*HD + w*16 + lm)*HD + lg*8;
    #pragma unroll
    for (int kc = 0; kc < 8; ++kc){
      wih[g][kc] = cvt8(pw + kc*32);
      whh[g][kc] = cvt8(ph + kc*32);
    }
  }

  int len_r[4];
  #pragma unroll
  for (int r = 0; r < 4; ++r) len_r[r] = lens[seqbase + lg*4 + r];

  float h_reg[4] = {0,0,0,0};
  float c_reg[4] = {0,0,0,0};

  const int* myrow = bi + (size_t)(seqbase + lm) * LS;
  const int  mycol = w*16 + lm;

  __syncthreads();

  int p = 0;
  for (int t = 0; t < LS; ++t){
    int idx = myrow[t];
    short8 xf[8];
    const float* xr = embf + (size_t)idx*ED + lg*8;
    #pragma unroll
    for (int kc = 0; kc < 8; ++kc) xf[kc] = cvt8(xr + kc*32);
    short8 hf[8];
    const short* hb = &hbuf[p][0];
    #pragma unroll
    for (int kc = 0; kc < 8; ++kc){
      int gr = kc*4 + lg;
      hf[kc] = *(const short8*)(hb + lm*256 + swz(lm, gr)*8);
    }
    f32x4 acc[4];
    #pragma unroll
    for (int g = 0; g < 4; ++g){ f32x4 a = {bias[g],bias[g],bias[g],bias[g]}; acc[g] = a; }
    #pragma unroll
    for (int kc = 0; kc < 8; ++kc){
      #pragma unroll
      for (int g = 0; g < 4; ++g)
        acc[g] = __builtin_amdgcn_mfma_f32_16x16x32_bf16(xf[kc], wih[g][kc], acc[g], 0, 0, 0);
    }
    #pragma unroll
    for (int kc = 0; kc < 8; ++kc){
      #pragma unroll
      for (int g = 0; g < 4; ++g)
        acc[g] = __builtin_amdgcn_mfma_f32_16x16x32_bf16(hf[kc], whh[g][kc], acc[g], 0, 0, 0);
    }
    short* hbn = &hbuf[p^1][0];
    #pragma unroll
    for (int r = 0; r < 4; ++r){
      float gi = sigm(acc[0][r]);
      float gf = sigm(acc[1][r]);
      float gg = tanh_f(acc[2][r]);
      float go = sigm(acc[3][r]);
      float cn = gf * c_reg[r] + gi * gg;
      float hn = go * tanh_f(cn);
      bool mk = (t < len_r[r]);
      c_reg[r] = mk ? cn : c_reg[r];
      h_reg[r] = mk ? hn : h_reg[r];
      int row = lg*4 + r;
      hbn[row*256 + swz(row, mycol >> 3)*8 + (mycol & 7)] = f2bf(h_reg[r]);
      enc[ ((size_t)(seqbase + row)*LS + t)*HD + mycol ] = mk ? hn : 0.f;
    }
    __syncthreads();
    p ^= 1;
  }
  #pragma unroll
  for (int r = 0; r < 4; ++r){
    int row = seqbase + lg*4 + r;
    hT[row*HD + mycol] = h_reg[r];
    cT[row*HD + mycol] = c_reg[r];
  }
}

// ---------------- kernel 4: branch LSTMs (4 steps, unmasked) --------------
__launch_bounds__(1024)
__global__ void k_branch(const float* __restrict__ stateH, const float* __restrict__ stateC,
                         const float* __restrict__ WiH, const float* __restrict__ WhH, const float* __restrict__ bH,
                         const float* __restrict__ WiC, const float* __restrict__ WhC, const float* __restrict__ bC,
                         const float* __restrict__ wgt,
                         float* __restrict__ PH, float* __restrict__ PC)
{
  const int branch = blockIdx.x >> 4;
  const int blk    = blockIdx.x & 15;
  const float* state = branch ? stateC : stateH;
  const float* Wi    = branch ? WiC : WiH;
  const float* Wh    = branch ? WhC : WhH;
  const float* bb    = branch ? bC  : bH;
  float* P           = branch ? PC  : PH;

  const int w  = threadIdx.x >> 6;
  const int l  = threadIdx.x & 63;
  const int lm = l & 15;
  const int lg = l >> 4;
  const int rbase = blk * 16;

  __shared__ short hbuf[2][16*256];
  for (int i = threadIdx.x; i < 16*256; i += 1024) hbuf[0][i] = 0;
  for (int i = threadIdx.x; i < 16*256; i += 1024)
    P[(size_t)(rbase + (i >> 8))*KP + UTT*HD + (i & 255)] = 0.f;

  float bias[4];
  #pragma unroll
  for (int g = 0; g < 4; ++g) bias[g] = bb[g*HD + w*16 + lm];

  short8 wih[4][8], whh[4][8];
  #pragma unroll
  for (int g = 0; g < 4; ++g){
    const float* pw = Wi + (size_t)(g*HD + w*16 + lm)*HD + lg*8;
    const float* ph = Wh + (size_t)(g*HD + w*16 + lm)*HD + lg*8;
    #pragma unroll
    for (int kc = 0; kc < 8; ++kc){
      wih[g][kc] = cvt8(pw + kc*32);
      whh[g][kc] = cvt8(ph + kc*32);
    }
  }

  float c_reg[4] = {0,0,0,0};
  __syncthreads();

  int p = 0;
  for (int u = 0; u < UTT; ++u){
    const float* xr = state + (size_t)((rbase + lm)*UTT + u)*HD + lg*8;
    short8 xf[8];
    #pragma unroll
    for (int kc = 0; kc < 8; ++kc) xf[kc] = cvt8(xr + kc*32);
    short8 hf[8];
    const short* hb = &hbuf[p][0];
    #pragma unroll
    for (int kc = 0; kc < 8; ++kc){
      int gr = kc*4 + lg;
      hf[kc] = *(const short8*)(hb + lm*256 + swz(lm, gr)*8);
    }
    f32x4 acc[4];
    #pragma unroll
    for (int g = 0; g < 4; ++g){ f32x4 a = {bias[g],bias[g],bias[g],bias[g]}; acc[g] = a; }
    #pragma unroll
    for (int kc = 0; kc < 8; ++kc){
      #pragma unroll
      for (int g = 0; g < 4; ++g)
        acc[g] = __builtin_amdgcn_mfma_f32_16x16x32_bf16(xf[kc], wih[g][kc], acc[g], 0, 0, 0);
    }
    #pragma unroll
    for (int kc = 0; kc < 8; ++kc){
      #pragma unroll
      for (int g = 0; g < 4; ++g)
        acc[g] = __builtin_amdgcn_mfma_f32_16x16x32_bf16(hf[kc], whh[g][kc], acc[g], 0, 0, 0);
    }
    short* hbn = &hbuf[p^1][0];
    #pragma unroll
    for (int r = 0; r < 4; ++r){
      float gi = sigm(acc[0][r]);
      float gf = sigm(acc[1][r]);
      float gg = tanh_f(acc[2][r]);
      float go = sigm(acc[3][r]);
      float cn = gf * c_reg[r] + gi * gg;
      float hn = go * tanh_f(cn);
      c_reg[r] = cn;
      int row = lg*4 + r, c = w*16 + lm;
      hbn[row*256 + swz(row, c >> 3)*8 + (c & 7)] = f2bf(hn);
      int b = rbase + row;
      P[(size_t)b*KP + u*HD + c] = hn * wgt[b*UTT + u];
    }
    __syncthreads();
    p ^= 1;
  }
}

// ---------------- kernel 5: final projection out = P @ Wl^T + bl ----------
__launch_bounds__(256)
__global__ void k_final(const float* __restrict__ PH, const float* __restrict__ PC,
                        const float* __restrict__ Wlh, const float* __restrict__ blh,
                        const float* __restrict__ Wlc, const float* __restrict__ blc,
                        float* __restrict__ outH, float* __restrict__ outC)
{
  const int branch = blockIdx.x >> 4;
  const int blk    = blockIdx.x & 15;
  const float* P  = branch ? PC  : PH;
  const float* Wl = branch ? Wlc : Wlh;
  const float* bl = branch ? blc : blh;
  float* out = branch ? outC : outH;

  const int w  = threadIdx.x >> 6;
  const int l  = threadIdx.x & 63;
  const int lm = l & 15;
  const int lg = l >> 4;
  const int rbase = blk * 16;

  f32x4 acc[4];
  #pragma unroll
  for (int j = 0; j < 4; ++j){
    float bv = bl[(w*4 + j)*16 + lm];
    f32x4 a = {bv, bv, bv, bv}; acc[j] = a;
  }
  for (int kc = 0; kc < 40; ++kc){
    short8 af = cvt8(P + (size_t)(rbase + lm)*KP + kc*32 + lg*8);
    #pragma unroll
    for (int j = 0; j < 4; ++j){
      int n = (w*4 + j)*16 + lm;
      short8 bf_ = cvt8(Wl + (size_t)n*KP + kc*32 + lg*8);
      acc[j] = __builtin_amdgcn_mfma_f32_16x16x32_bf16(af, bf_, acc[j], 0, 0, 0);
    }
  }
  #pragma unroll
  for (int j = 0; j < 4; ++j)
    #pragma unroll
    for (int r = 0; r < 4; ++r)
      out[(size_t)(rbase + lg*4 + r)*HD + (w*4 + j)*16 + lm] = acc[j][r];
}

// ---------------- launch ---------------------------------------------------
extern "C" void kernel_launch(void* const* d_in, const int* in_sizes, int n_in,
                              void* d_out, int out_size, void* d_ws, size_t ws_size,
                              hipStream_t stream)
{
  (void)in_sizes; (void)n_in; (void)out_size;
  const int*   bi   = (const int*)  d_in[0];
  const int*   lens = (const int*)  d_in[1];
  const float* emb  = (const float*)d_in[7];
  const float* Wih  = (const float*)d_in[8];
  const float* Whh  = (const float*)d_in[9];
  const float* bb   = (const float*)d_in[10];
  const float* WiH  = (const float*)d_in[11];
  const float* WhH  = (const float*)d_in[12];
  const float* bH   = (const float*)d_in[13];
  const float* WiC  = (const float*)d_in[14];
  const float* WhC  = (const float*)d_in[15];
  const float* bC   = (const float*)d_in[16];
  const float* Wlh  = (const float*)d_in[17];
  const float* blh  = (const float*)d_in[18];
  const float* Wlc  = (const float*)d_in[19];
  const float* blc  = (const float*)d_in[20];

  // ws layout (float offsets): se | wgt | hT | cT | PH | PC | flags
  // byte offsets: WihB @6MB (512KB) | hx @6.5MB (1MB) | proj @8MB (62.5MB)
  float* ws  = (float*)d_ws;
  float* se  = ws;
  float* wgt = ws + 262144;
  float* hT  = ws + 263168;
  float* cT  = ws + 525312;
  float* PH  = ws + 787456;
  float* PC  = ws + 1115136;
  int*   flags = (int*)(ws + 1442816);
  unsigned short* WihB = (unsigned short*)((char*)d_ws + (6u  << 20));
  unsigned short* hx   = (unsigned short*)((char*)d_ws + 6815744u);
  unsigned short* proj = (unsigned short*)((char*)d_ws + (8u  << 20));
  const size_t NEED = (8ull << 20) + 2ull * 32000 * 1024;   // ~70.5 MB
  const bool fast = (ws_size >= NEED);

  float* enc  = (float*)d_out;
  float* outH = enc + (size_t)NSEQ * LS * HD;
  float* outC = outH + (size_t)BSZ * HD;

  k_se    <<<NSEQ, 256, 0, stream>>>(bi, emb, se);
  k_weight<<<BSZ,   64, 0, stream>>>(se, wgt);
  if (fast){
    k_init <<<1, 128, 0, stream>>>(flags);
    k_cvtW <<<128, 256, 0, stream>>>(Wih, WihB, 32768);
    k_proj <<<1000, 256, 0, stream>>>(emb, WihB, bb, proj);
    k_rec  <<<128, 512, 0, stream>>>(bi, lens, proj, Whh, enc, hT, cT, hx, flags);
  } else {
    k_lstm_main<<<64, 1024, 0, stream>>>(bi, lens, emb, Wih, Whh, bb, enc, hT, cT);
  }
  k_branch<<<32, 1024, 0, stream>>>(hT, cT, WiH, WhH, bH, WiC, WhC, bC, wgt, PH, PC);
  k_final <<<32,  256, 0, stream>>>(PH, PC, Wlh, blh, Wlc, blc, outH, outC);
}

// Round 4
// 892.811 us; speedup vs baseline: 4.4332x; 2.1490x over previous
//
#include <hip/hip_runtime.h>
#include <hip/hip_bf16.h>

// Problem constants (fixed-shape problem)
#define NSEQ 1024   // N = (N_UTT-1)*B
#define LS   128    // L
#define ED   256    // E
#define HD   256    // H
#define BSZ  256    // batch
#define UTT  4      // U = n-1
#define KP   1280   // (MAX_UTT-1)*H

using short8 = __attribute__((ext_vector_type(8))) short;
using f32x4  = __attribute__((ext_vector_type(4))) float;

union S8 { short8 s; unsigned u[4]; };

__device__ __forceinline__ unsigned pack_bf2(float a, float b){
  unsigned ua = __builtin_bit_cast(unsigned, a);
  unsigned ub = __builtin_bit_cast(unsigned, b);
  return ((ua + 0x8000u) >> 16) | ((ub + 0x8000u) & 0xFFFF0000u);
}
__device__ __forceinline__ unsigned short f2bf(float a){
  return (unsigned short)((__builtin_bit_cast(unsigned, a) + 0x8000u) >> 16);
}
__device__ __forceinline__ float bf2f(unsigned short u){
  unsigned v = ((unsigned)u) << 16;
  return __builtin_bit_cast(float, v);
}
// convert 8 consecutive f32 -> short8 of bf16 bits
__device__ __forceinline__ short8 cvt8(const float* __restrict__ p){
  float4 a = ((const float4*)p)[0];
  float4 b = ((const float4*)p)[1];
  S8 s;
  s.u[0] = pack_bf2(a.x, a.y); s.u[1] = pack_bf2(a.z, a.w);
  s.u[2] = pack_bf2(b.x, b.y); s.u[3] = pack_bf2(b.z, b.w);
  return s.s;
}
__device__ __forceinline__ float sigm(float x){ return 1.0f/(1.0f + exp2f(-1.44269504f*x)); }
__device__ __forceinline__ float tanh_f(float x){ return 2.0f/(1.0f + exp2f(-2.88539008f*x)) - 1.0f; }
__device__ __forceinline__ int swz(int row, int gr){ return (gr & 24) | ((gr ^ row) & 7); }

// ---------------- init: zero sync flags (must run each launch; replay-safe)
__global__ void k_init(int* __restrict__ flags){
  flags[threadIdx.x] = 0;
}

// ---------------- cvt Wih f32 -> bf16 -------------------------------------
__global__ void k_cvtW(const float* __restrict__ e, unsigned short* __restrict__ o, int n8){
  int i = blockIdx.x * blockDim.x + threadIdx.x;
  if (i < n8) *(short8*)(o + (size_t)i*8) = cvt8(e + (size_t)i*8);
}

// ---------------- vocab projection: proj[v][g*256+c] = Wih@emb[v] + b ------
__launch_bounds__(256, 2)
__global__ void k_proj(const float* __restrict__ emb, const unsigned short* __restrict__ WihB,
                       const float* __restrict__ bb, unsigned short* __restrict__ proj)
{
  const int g  = threadIdx.x >> 6;    // gate 0..3
  const int l  = threadIdx.x & 63;
  const int lm = l & 15;
  const int lg = l >> 4;
  const int vbase = blockIdx.x * 32;

  f32x4 acc[2][16];
  #pragma unroll
  for (int j = 0; j < 16; ++j){
    float bv = bb[g*256 + j*16 + lm];
    f32x4 a = {bv, bv, bv, bv};
    acc[0][j] = a; acc[1][j] = a;
  }
  for (int kc = 0; kc < 8; ++kc){
    short8 af0 = cvt8(emb + (size_t)(vbase + lm)*ED + kc*32 + lg*8);
    short8 af1 = cvt8(emb + (size_t)(vbase + 16 + lm)*ED + kc*32 + lg*8);
    #pragma unroll
    for (int j = 0; j < 16; ++j){
      short8 bf_ = *(const short8*)(WihB + (size_t)(g*256 + j*16 + lm)*ED + kc*32 + lg*8);
      acc[0][j] = __builtin_amdgcn_mfma_f32_16x16x32_bf16(af0, bf_, acc[0][j], 0, 0, 0);
      acc[1][j] = __builtin_amdgcn_mfma_f32_16x16x32_bf16(af1, bf_, acc[1][j], 0, 0, 0);
    }
  }
  #pragma unroll
  for (int m2 = 0; m2 < 2; ++m2)
    #pragma unroll
    for (int j = 0; j < 16; ++j)
      #pragma unroll
      for (int r = 0; r < 4; ++r){
        int v = vbase + m2*16 + lg*4 + r;
        proj[(size_t)v*1024 + g*256 + j*16 + lm] = f2bf(acc[m2][j][r]);
      }
}

// ---------------- kernel 1: se[seq][e] = sum_t emb[idx[seq][t]][e] --------
__global__ void k_se(const int* __restrict__ bi, const float* __restrict__ emb,
                     float* __restrict__ se){
  int seq = blockIdx.x, e = threadIdx.x;
  const int* row = bi + seq * LS;
  float acc = 0.f;
  #pragma unroll 4
  for (int t = 0; t < LS; ++t) acc += emb[(size_t)row[t]*ED + e];
  se[seq*ED + e] = acc;
}

// ---------------- kernel 2: cosine + softmax -> weight[b][u] --------------
__global__ void k_weight(const float* __restrict__ se, float* __restrict__ wgt){
  int b = blockIdx.x, l = threadIdx.x;  // 64 threads
  const float* s3 = se + (b*UTT + 3)*ED;
  float dots[UTT], nn[UTT];
  #pragma unroll
  for (int u = 0; u < UTT; ++u){
    const float* su = se + (b*UTT + u)*ED;
    float d = 0.f, q = 0.f;
    for (int k = l; k < ED; k += 64){ float a = su[k]; d += a * s3[k]; q += a * a; }
    #pragma unroll
    for (int off = 32; off; off >>= 1){ d += __shfl_xor(d, off); q += __shfl_xor(q, off); }
    dots[u] = d; nn[u] = q;
  }
  if (l == 0){
    float n3 = fmaxf(sqrtf(nn[3]), 1e-8f);
    float c[UTT], m = -1e30f;
    #pragma unroll
    for (int u = 0; u < UTT; ++u){
      float nu = fmaxf(sqrtf(nn[u]), 1e-8f);
      c[u] = dots[u] / (nu * n3);
      m = fmaxf(m, c[u]);
    }
    float s = 0.f;
    #pragma unroll
    for (int u = 0; u < UTT; ++u){ c[u] = exp2f(1.44269504f*(c[u]-m)); s += c[u]; }
    #pragma unroll
    for (int u = 0; u < UTT; ++u) wgt[b*UTT + u] = c[u] / s;
  }
}

// ---------------- cooperative recurrence (2-way column split) --------------
// 128 blocks: slice s = bid>>6 (cols [s*128, s*128+128)), group g = bid&63
// (seqs 16g..16g+15). All cross-block exchange through agent-scope RELAXED
// atomics at the LLC (no cache-flush fences!). Per step: partner h-half is
// staged once into LDS (coalesced u32 atomic loads), own half stored as
// lane-paired u32s; flag set after s_waitcnt vmcnt(0) + block barrier.
__device__ __forceinline__ void load_xp(const int* __restrict__ bi,
                                        const unsigned short* __restrict__ proj,
                                        int sb, int lg, int mycol, int t,
                                        float xp[4][4]){
  #pragma unroll
  for (int r = 0; r < 4; ++r){
    int tok = bi[(sb + lg*4 + r)*LS + t];
    const unsigned short* pr = proj + (size_t)tok*1024 + mycol;
    #pragma unroll
    for (int q = 0; q < 4; ++q) xp[q][r] = bf2f(pr[q*256]);
  }
}

#define HSTRIDE 264   // LDS row stride in u16 (132 dwords -> worst 2-way conflict, free)

__launch_bounds__(512, 2)
__global__ void k_rec(const int* __restrict__ bi, const int* __restrict__ lens,
                      const unsigned short* __restrict__ proj,
                      const float* __restrict__ Whh,
                      float* __restrict__ enc,
                      float* __restrict__ hT, float* __restrict__ cT,
                      unsigned* __restrict__ hx, int* __restrict__ flags)
{
  const int s    = blockIdx.x >> 6;       // column slice 0/1
  const int gidx = blockIdx.x & 63;       // seq group
  const int w  = threadIdx.x >> 6;        // wave 0..7
  const int l  = threadIdx.x & 63;
  const int lm = l & 15;
  const int lg = l >> 4;
  const int sb = gidx * 16;
  const int mycol = s*128 + w*16 + lm;

  __shared__ unsigned short htile[2][16 * HSTRIDE];  // full 256-col h, dbuf

  // persistent Whh fragments: 4 gates x 8 k-chunks (128 VGPR)
  short8 whh[4][8];
  #pragma unroll
  for (int q = 0; q < 4; ++q){
    const float* ph = Whh + (size_t)(q*HD + mycol)*HD + lg*8;
    #pragma unroll
    for (int kc = 0; kc < 8; ++kc) whh[q][kc] = cvt8(ph + kc*32);
  }

  int len_r[4];
  #pragma unroll
  for (int r = 0; r < 4; ++r) len_r[r] = lens[sb + lg*4 + r];

  float h_reg[4] = {0,0,0,0};
  float c_reg[4] = {0,0,0,0};

  int* myflag = flags + gidx*2 + s;
  int* pflag  = flags + gidx*2 + (1 - s);
  // hx layout (u32 units): [buf][group][slice][seq 16][col-pair 64]
  #define HXB32(buf, s2) ( (((size_t)(buf)*64 + gidx)*2 + (s2)) * 1024 )

  float xpc[4][4], xpn[4][4];
  load_xp(bi, proj, sb, lg, mycol, 0, xpc);

  for (int t = 0; t < LS; ++t){
    if (t > 0){
      // ---- wait for partner's h(t-1) flag (LLC atomic poll) ----
      int guard = 0;
      while (__hip_atomic_load(pflag, __ATOMIC_RELAXED, __HIP_MEMORY_SCOPE_AGENT) < t){
        if (++guard > (1 << 18)) break;
        __builtin_amdgcn_s_sleep(2);
      }
      asm volatile("" ::: "memory");
      // ---- stage partner half -> LDS (coalesced, 8 B/thread) ----
      {
        const unsigned* src = hx + HXB32((t-1)&1, 1-s);
        int tid = threadIdx.x;
        int r  = tid >> 5;            // 16 rows
        int c2 = (tid & 31) * 2;      // u32 pair within 64-u32 row
        unsigned a = __hip_atomic_load(src + r*64 + c2,     __ATOMIC_RELAXED, __HIP_MEMORY_SCOPE_AGENT);
        unsigned b = __hip_atomic_load(src + r*64 + c2 + 1, __ATOMIC_RELAXED, __HIP_MEMORY_SCOPE_AGENT);
        unsigned* dst = (unsigned*)(&htile[(t-1)&1][0] + r*HSTRIDE + (1-s)*128 + c2*2);
        dst[0] = a; dst[1] = b;
      }
    }
    __syncthreads();   // BAR1: h(t-1) tile complete (own half written last iter)

    // ---- prefetch next step's input projection ----
    if (t + 1 < LS) load_xp(bi, proj, sb, lg, mycol, t + 1, xpn);

    // ---- gates = xp + h(t-1) @ Whh_slice^T ----
    f32x4 acc[4];
    #pragma unroll
    for (int q = 0; q < 4; ++q){
      f32x4 a = {xpc[q][0], xpc[q][1], xpc[q][2], xpc[q][3]};
      acc[q] = a;
    }
    if (t > 0){
      const unsigned short* hb = &htile[(t-1)&1][0];
      #pragma unroll
      for (int kc = 0; kc < 8; ++kc){
        short8 hf = *(const short8*)(hb + lm*HSTRIDE + kc*32 + lg*8);
        #pragma unroll
        for (int q = 0; q < 4; ++q)
          acc[q] = __builtin_amdgcn_mfma_f32_16x16x32_bf16(hf, whh[q][kc], acc[q], 0, 0, 0);
      }
    }

    // ---- cell update ----
    unsigned short* lown = &htile[t&1][0];
    #pragma unroll
    for (int r = 0; r < 4; ++r){
      float gi = sigm(acc[0][r]);
      float gf = sigm(acc[1][r]);
      float gg = tanh_f(acc[2][r]);
      float go = sigm(acc[3][r]);
      float cn = gf * c_reg[r] + gi * gg;
      float hn = go * tanh_f(cn);
      bool mk = (t < len_r[r]);
      c_reg[r] = mk ? cn : c_reg[r];
      h_reg[r] = mk ? hn : h_reg[r];
      int row = lg*4 + r;
      lown[row*HSTRIDE + mycol] = f2bf(h_reg[r]);
      __builtin_nontemporal_store(mk ? hn : 0.f,
          enc + ((size_t)(sb + row)*LS + t)*HD + mycol);
    }
    // ---- own half -> LLC as lane-paired u32 (all-32-bit atomics) ----
    {
      unsigned* hxw = hx + HXB32(t&1, s);
      #pragma unroll
      for (int r = 0; r < 4; ++r){
        float other = __shfl_xor(h_reg[r], 1);
        if (!(lm & 1)){
          unsigned pv = pack_bf2(h_reg[r], other);
          __hip_atomic_store(hxw + (lg*4 + r)*64 + ((w*16 + lm) >> 1), pv,
                             __ATOMIC_RELAXED, __HIP_MEMORY_SCOPE_AGENT);
        }
      }
    }
    asm volatile("s_waitcnt vmcnt(0)" ::: "memory");   // stores at coherence point
    __syncthreads();   // BAR2: whole block drained
    if (threadIdx.x == 0)
      __hip_atomic_store(myflag, t + 1, __ATOMIC_RELAXED, __HIP_MEMORY_SCOPE_AGENT);

    #pragma unroll
    for (int q = 0; q < 4; ++q)
      #pragma unroll
      for (int r = 0; r < 4; ++r) xpc[q][r] = xpn[q][r];
  }
  #pragma unroll
  for (int r = 0; r < 4; ++r){
    int row = sb + lg*4 + r;
    hT[(size_t)row*HD + mycol] = h_reg[r];
    cT[(size_t)row*HD + mycol] = c_reg[r];
  }
  #undef HXB32
}

// ---------------- fallback main LSTM (round-2 proven, ws-limited path) ----
__launch_bounds__(1024)
__global__ void k_lstm_main(const int* __restrict__ bi, const int* __restrict__ lens,
                            const float* __restrict__ embf,
                            const float* __restrict__ Wih, const float* __restrict__ Whh,
                            const float* __restrict__ bb,
                            float* __restrict__ enc,
                            float* __restrict__ hT, float* __restrict__ cT)
{
  const int w  = threadIdx.x >> 6;
  const int l  = threadIdx.x & 63;
  const int lm = l & 15;
  const int lg = l >> 4;
  const int seqbase = blockIdx.x * 16;

  __shared__ short hbuf[2][16*256];
  for (int i = threadIdx.x; i < 16*256; i += 1024) hbuf[0][i] = 0;

  float bias[4];
  #pragma unroll
  for (int g = 0; g < 4; ++g) bias[g] = bb[g*HD + w*16 + lm];

  short8 wih[4][8], whh[4][8];
  #pragma unroll
  for (int g = 0; g < 4; ++g){
    const float* pw = Wih + (size_t)(g*HD + w*16 + lm)*ED + lg*8;
    const float* ph = Whh + (size_t)(g*HD + w*16 + lm)*HD + lg*8;
    #pragma unroll
    for (int kc = 0; kc < 8; ++kc){
      wih[g][kc] = cvt8(pw + kc*32);
      whh[g][kc] = cvt8(ph + kc*32);
    }
  }

  int len_r[4];
  #pragma unroll
  for (int r = 0; r < 4; ++r) len_r[r] = lens[seqbase + lg*4 + r];

  float h_reg[4] = {0,0,0,0};
  float c_reg[4] = {0,0,0,0};

  const int* myrow = bi + (size_t)(seqbase + lm) * LS;
  const int  mycol = w*16 + lm;

  __syncthreads();

  int p = 0;
  for (int t = 0; t < LS; ++t){
    int idx = myrow[t];
    short8 xf[8];
    const float* xr = embf + (size_t)idx*ED + lg*8;
    #pragma unroll
    for (int kc = 0; kc < 8; ++kc) xf[kc] = cvt8(xr + kc*32);
    short8 hf[8];
    const short* hb = &hbuf[p][0];
    #pragma unroll
    for (int kc = 0; kc < 8; ++kc){
      int gr = kc*4 + lg;
      hf[kc] = *(const short8*)(hb + lm*256 + swz(lm, gr)*8);
    }
    f32x4 acc[4];
    #pragma unroll
    for (int g = 0; g < 4; ++g){ f32x4 a = {bias[g],bias[g],bias[g],bias[g]}; acc[g] = a; }
    #pragma unroll
    for (int kc = 0; kc < 8; ++kc){
      #pragma unroll
      for (int g = 0; g < 4; ++g)
        acc[g] = __builtin_amdgcn_mfma_f32_16x16x32_bf16(xf[kc], wih[g][kc], acc[g], 0, 0, 0);
    }
    #pragma unroll
    for (int kc = 0; kc < 8; ++kc){
      #pragma unroll
      for (int g = 0; g < 4; ++g)
        acc[g] = __builtin_amdgcn_mfma_f32_16x16x32_bf16(hf[kc], whh[g][kc], acc[g], 0, 0, 0);
    }
    short* hbn = &hbuf[p^1][0];
    #pragma unroll
    for (int r = 0; r < 4; ++r){
      float gi = sigm(acc[0][r]);
      float gf = sigm(acc[1][r]);
      float gg = tanh_f(acc[2][r]);
      float go = sigm(acc[3][r]);
      float cn = gf * c_reg[r] + gi * gg;
      float hn = go * tanh_f(cn);
      bool mk = (t < len_r[r]);
      c_reg[r] = mk ? cn : c_reg[r];
      h_reg[r] = mk ? hn : h_reg[r];
      int row = lg*4 + r;
      hbn[row*256 + swz(row, mycol >> 3)*8 + (mycol & 7)] = f2bf(h_reg[r]);
      enc[ ((size_t)(seqbase + row)*LS + t)*HD + mycol ] = mk ? hn : 0.f;
    }
    __syncthreads();
    p ^= 1;
  }
  #pragma unroll
  for (int r = 0; r < 4; ++r){
    int row = seqbase + lg*4 + r;
    hT[row*HD + mycol] = h_reg[r];
    cT[row*HD + mycol] = c_reg[r];
  }
}

// ---------------- kernel 4: branch LSTMs (4 steps, unmasked) --------------
__launch_bounds__(1024)
__global__ void k_branch(const float* __restrict__ stateH, const float* __restrict__ stateC,
                         const float* __restrict__ WiH, const float* __restrict__ WhH, const float* __restrict__ bH,
                         const float* __restrict__ WiC, const float* __restrict__ WhC, const float* __restrict__ bC,
                         const float* __restrict__ wgt,
                         float* __restrict__ PH, float* __restrict__ PC)
{
  const int branch = blockIdx.x >> 4;
  const int blk    = blockIdx.x & 15;
  const float* state = branch ? stateC : stateH;
  const float* Wi    = branch ? WiC : WiH;
  const float* Wh    = branch ? WhC : WhH;
  const float* bb    = branch ? bC  : bH;
  float* P           = branch ? PC  : PH;

  const int w  = threadIdx.x >> 6;
  const int l  = threadIdx.x & 63;
  const int lm = l & 15;
  const int lg = l >> 4;
  const int rbase = blk * 16;

  __shared__ short hbuf[2][16*256];
  for (int i = threadIdx.x; i < 16*256; i += 1024) hbuf[0][i] = 0;
  for (int i = threadIdx.x; i < 16*256; i += 1024)
    P[(size_t)(rbase + (i >> 8))*KP + UTT*HD + (i & 255)] = 0.f;

  float bias[4];
  #pragma unroll
  for (int g = 0; g < 4; ++g) bias[g] = bb[g*HD + w*16 + lm];

  short8 wih[4][8], whh[4][8];
  #pragma unroll
  for (int g = 0; g < 4; ++g){
    const float* pw = Wi + (size_t)(g*HD + w*16 + lm)*HD + lg*8;
    const float* ph = Wh + (size_t)(g*HD + w*16 + lm)*HD + lg*8;
    #pragma unroll
    for (int kc = 0; kc < 8; ++kc){
      wih[g][kc] = cvt8(pw + kc*32);
      whh[g][kc] = cvt8(ph + kc*32);
    }
  }

  float c_reg[4] = {0,0,0,0};
  __syncthreads();

  int p = 0;
  for (int u = 0; u < UTT; ++u){
    const float* xr = state + (size_t)((rbase + lm)*UTT + u)*HD + lg*8;
    short8 xf[8];
    #pragma unroll
    for (int kc = 0; kc < 8; ++kc) xf[kc] = cvt8(xr + kc*32);
    short8 hf[8];
    const short* hb = &hbuf[p][0];
    #pragma unroll
    for (int kc = 0; kc < 8; ++kc){
      int gr = kc*4 + lg;
      hf[kc] = *(const short8*)(hb + lm*256 + swz(lm, gr)*8);
    }
    f32x4 acc[4];
    #pragma unroll
    for (int g = 0; g < 4; ++g){ f32x4 a = {bias[g],bias[g],bias[g],bias[g]}; acc[g] = a; }
    #pragma unroll
    for (int kc = 0; kc < 8; ++kc){
      #pragma unroll
      for (int g = 0; g < 4; ++g)
        acc[g] = __builtin_amdgcn_mfma_f32_16x16x32_bf16(xf[kc], wih[g][kc], acc[g], 0, 0, 0);
    }
    #pragma unroll
    for (int kc = 0; kc < 8; ++kc){
      #pragma unroll
      for (int g = 0; g < 4; ++g)
        acc[g] = __builtin_amdgcn_mfma_f32_16x16x32_bf16(hf[kc], whh[g][kc], acc[g], 0, 0, 0);
    }
    short* hbn = &hbuf[p^1][0];
    #pragma unroll
    for (int r = 0; r < 4; ++r){
      float gi = sigm(acc[0][r]);
      float gf = sigm(acc[1][r]);
      float gg = tanh_f(acc[2][r]);
      float go = sigm(acc[3][r]);
      float cn = gf * c_reg[r] + gi * gg;
      float hn = go * tanh_f(cn);
      c_reg[r] = cn;
      int row = lg*4 + r, c = w*16 + lm;
      hbn[row*256 + swz(row, c >> 3)*8 + (c & 7)] = f2bf(hn);
      int b = rbase + row;
      P[(size_t)b*KP + u*HD + c] = hn * wgt[b*UTT + u];
    }
    __syncthreads();
    p ^= 1;
  }
}

// ---------------- kernel 5: final projection out = P @ Wl^T + bl ----------
__launch_bounds__(256)
__global__ void k_final(const float* __restrict__ PH, const float* __restrict__ PC,
                        const float* __restrict__ Wlh, const float* __restrict__ blh,
                        const float* __restrict__ Wlc, const float* __restrict__ blc,
                        float* __restrict__ outH, float* __restrict__ outC)
{
  const int branch = blockIdx.x >> 4;
  const int blk    = blockIdx.x & 15;
  const float* P  = branch ? PC  : PH;
  const float* Wl = branch ? Wlc : Wlh;
  const float* bl = branch ? blc : blh;
  float* out = branch ? outC : outH;

  const int w  = threadIdx.x >> 6;
  const int l  = threadIdx.x & 63;
  const int lm = l & 15;
  const int lg = l >> 4;
  const int rbase = blk * 16;

  f32x4 acc[4];
  #pragma unroll
  for (int j = 0; j < 4; ++j){
    float bv = bl[(w*4 + j)*16 + lm];
    f32x4 a = {bv, bv, bv, bv}; acc[j] = a;
  }
  for (int kc = 0; kc < 40; ++kc){
    short8 af = cvt8(P + (size_t)(rbase + lm)*KP + kc*32 + lg*8);
    #pragma unroll
    for (int j = 0; j < 4; ++j){
      int n = (w*4 + j)*16 + lm;
      short8 bf_ = cvt8(Wl + (size_t)n*KP + kc*32 + lg*8);
      acc[j] = __builtin_amdgcn_mfma_f32_16x16x32_bf16(af, bf_, acc[j], 0, 0, 0);
    }
  }
  #pragma unroll
  for (int j = 0; j < 4; ++j)
    #pragma unroll
    for (int r = 0; r < 4; ++r)
      out[(size_t)(rbase + lg*4 + r)*HD + (w*4 + j)*16 + lm] = acc[j][r];
}

// ---------------- launch ---------------------------------------------------
extern "C" void kernel_launch(void* const* d_in, const int* in_sizes, int n_in,
                              void* d_out, int out_size, void* d_ws, size_t ws_size,
                              hipStream_t stream)
{
  (void)in_sizes; (void)n_in; (void)out_size;
  const int*   bi   = (const int*)  d_in[0];
  const int*   lens = (const int*)  d_in[1];
  const float* emb  = (const float*)d_in[7];
  const float* Wih  = (const float*)d_in[8];
  const float* Whh  = (const float*)d_in[9];
  const float* bb   = (const float*)d_in[10];
  const float* WiH  = (const float*)d_in[11];
  const float* WhH  = (const float*)d_in[12];
  const float* bH   = (const float*)d_in[13];
  const float* WiC  = (const float*)d_in[14];
  const float* WhC  = (const float*)d_in[15];
  const float* bC   = (const float*)d_in[16];
  const float* Wlh  = (const float*)d_in[17];
  const float* blh  = (const float*)d_in[18];
  const float* Wlc  = (const float*)d_in[19];
  const float* blc  = (const float*)d_in[20];

  // ws layout (float offsets): se | wgt | hT | cT | PH | PC | flags
  // byte offsets: WihB @6MB (512KB) | hx @6.5MB (1MB) | proj @8MB (62.5MB)
  float* ws  = (float*)d_ws;
  float* se  = ws;
  float* wgt = ws + 262144;
  float* hT  = ws + 263168;
  float* cT  = ws + 525312;
  float* PH  = ws + 787456;
  float* PC  = ws + 1115136;
  int*   flags = (int*)(ws + 1442816);
  unsigned short* WihB = (unsigned short*)((char*)d_ws + (6u  << 20));
  unsigned*       hx   = (unsigned*)((char*)d_ws + 6815744u);
  unsigned short* proj = (unsigned short*)((char*)d_ws + (8u  << 20));
  const size_t NEED = (8ull << 20) + 2ull * 32000 * 1024;   // ~70.5 MB
  const bool fast = (ws_size >= NEED);

  float* enc  = (float*)d_out;
  float* outH = enc + (size_t)NSEQ * LS * HD;
  float* outC = outH + (size_t)BSZ * HD;

  k_se    <<<NSEQ, 256, 0, stream>>>(bi, emb, se);
  k_weight<<<BSZ,   64, 0, stream>>>(se, wgt);
  if (fast){
    k_init <<<1, 128, 0, stream>>>(flags);
    k_cvtW <<<128, 256, 0, stream>>>(Wih, WihB, 32768);
    k_proj <<<1000, 256, 0, stream>>>(emb, WihB, bb, proj);
    k_rec  <<<128, 512, 0, stream>>>(bi, lens, proj, Whh, enc, hT, cT, hx, flags);
  } else {
    k_lstm_main<<<64, 1024, 0, stream>>>(bi, lens, emb, Wih, Whh, bb, enc, hT, cT);
  }
  k_branch<<<32, 1024, 0, stream>>>(hT, cT, WiH, WhH, bH, WiC, WhC, bC, wgt, PH, PC);
  k_final <<<32,  256, 0, stream>>>(PH, PC, Wlh, blh, Wlc, blc, outH, outC);
}